// Round 17
// baseline (448.728 us; speedup 1.0000x reference)
//
#include <hip/hip_runtime.h>
#include <math.h>

#define G 200
#define N0 512
#define NE 614400          // G*N0*6
#define EPG 3072           // edges per graph (slot-stable across layers)
#define K1 410
#define K2 328
#define K3 263
#define H 128
#define NT0 102400         // G*N0
#define NT1 82000          // G*K1
#define NT2 65600          // G*K2
#define NT3 52600          // G*K3

// fixed-point scales for deterministic integer aggregation
#define SCALE1 1048576.0f        // 2^20, layer-1 features (|x| <= ~6)
#define INV1   (1.0f / 1048576.0f)
#define SCALE2 262144.0f         // 2^18, layers 2/3 (messages <= ~300, agg <= ~8000)
#define INV2   (1.0f / 262144.0f)

#define DEAD 0xFFFFu
#define RPS (N0 + 1)             // rowptr stride per graph

static inline int cdiv(int a, int b) { return (a + b - 1) / b; }

// ---- layer 1 MEGA-FUSED: agg6 + conv1 + score + topk + pool + readout + CSR ----
// one block (512 threads) per graph. Phase 1 = R16's agg6_conv1 (bit-identical
// h; score kept in LDS scL, never hits global). Phase 2 = R16's proven
// topk_pool body reading scL (bit-identical hout/z/CSR; h re-read from global
// is intra-block visible after __syncthreads, L1-warm). LDS: phase unions
// (52.2 KB | 26.7 KB) + 2 KB scL = 54.3 KB.
__global__ __launch_bounds__(512) void layer1_kernel(
    const float* __restrict__ x, const int* __restrict__ ei,
    const float* __restrict__ Wrel, const float* __restrict__ Wroot,
    const float* __restrict__ b, const float* __restrict__ pw,
    float* __restrict__ h, float* __restrict__ hout, float* __restrict__ z,
    int* __restrict__ out_s, int* __restrict__ out_d,
    int* __restrict__ rowptr, unsigned short* __restrict__ col) {
    __shared__ union {
        struct {
            float xs[N0 * 8];
            int   ag[N0 * 8];
            ushort2 eloc[EPG];
            float wrelL[768], wrootL[768], bL[128], pwL[128];
        } p1;
        struct {
            float sv[512];
            int si[512];
            int invL[512];
            float smax[4][128];
            float ssum[4][128];
            ushort2 eloc[EPG];
            int cnt[512];
            int basep[512];
            int wsum[8];
        } p2;
    } u;
    __shared__ float scL[512];
    const int g = blockIdx.x;
    const int t = threadIdx.x;
    const int base = g * N0;
    const int e0 = g * EPG;
    const int n = N0, k = K1;

    // ---------- phase 1: agg6 + conv1 + score (R16 agg6_conv1 body) ----------
    for (int i = t; i < N0 * 8; i += 512) {
        int m = i >> 3, j = i & 7;
        u.p1.xs[i] = (j < 6) ? x[(size_t)(base + m) * 6 + j] : 0.f;
        u.p1.ag[i] = 0;
    }
    for (int i = t; i < EPG; i += 512) {
        u.p1.eloc[i] = make_ushort2((unsigned short)(ei[e0 + i] - base),
                                    (unsigned short)(ei[NE + e0 + i] - base));
    }
    for (int i = t; i < 768; i += 512) { u.p1.wrelL[i] = Wrel[i]; u.p1.wrootL[i] = Wroot[i]; }
    if (t < 128) { u.p1.bL[t] = b[t]; u.p1.pwL[t] = pw[t]; }
    __syncthreads();
    const int sub8 = t >> 3;   // 64 subgroups of 8 lanes
    const int f8 = t & 7;
#pragma unroll 4
    for (int e = sub8; e < EPG; e += 64) {
        ushort2 p = u.p1.eloc[e];
        if (f8 < 6) {
            float v = u.p1.xs[p.x * 8 + f8];
            atomicAdd(&u.p1.ag[p.y * 8 + f8], __float2int_rn(v * SCALE1));
        }
    }
    __syncthreads();
    {
        const int nsub = t >> 5;
        const int lane = t & 31;
        const int o4 = lane * 4;
        for (int m = nsub; m < N0; m += 16) {
            float a[6], xv[6];
#pragma unroll
            for (int f = 0; f < 6; f++) {
                a[f] = (float)u.p1.ag[m * 8 + f] * INV1;
                xv[f] = u.p1.xs[m * 8 + f];
            }
            float4 r; float* rp = (float*)&r;
            float d = 0.f, n2 = 0.f;
#pragma unroll
            for (int j = 0; j < 4; j++) {
                int o = o4 + j;
                float acc = u.p1.bL[o];
#pragma unroll
                for (int f = 0; f < 6; f++)
                    acc += a[f] * u.p1.wrelL[o * 6 + f] + xv[f] * u.p1.wrootL[o * 6 + f];
                float hv = fmaxf(acc, 0.f);
                rp[j] = hv;
                float wv = u.p1.pwL[o];
                d = fmaf(hv, wv, d);
                n2 = fmaf(wv, wv, n2);
            }
            *(float4*)(h + (size_t)(base + m) * H + o4) = r;
#pragma unroll
            for (int s = 1; s < 32; s <<= 1) {
                d += __shfl_xor(d, s);
                n2 += __shfl_xor(n2, s);
            }
            if (lane == 0) scL[m] = tanhf(d / sqrtf(n2));
        }
    }
    __syncthreads();   // phase boundary: scL + global h visible; p1 LDS dead

    // ---------- phase 2: topk + gather/readout + CSR (R16 topk_pool body) ----------
    float v = scL[t];       // n == 512: every t valid
    int idx = t;
    for (int size = 2; size <= 512; size <<= 1) {
        const bool desc = ((t & size) == 0);
        for (int stride = size >> 1; stride > 0; stride >>= 1) {
            float pv; int pi;
            if (stride >= 64) {
                u.p2.sv[t] = v; u.p2.si[t] = idx;
                __syncthreads();
                pv = u.p2.sv[t ^ stride]; pi = u.p2.si[t ^ stride];
                __syncthreads();
            } else {
                pv = __shfl_xor(v, stride);
                pi = __shfl_xor(idx, stride);
            }
            const bool left = ((t & stride) == 0);
            const bool want_max = (desc == left);
            const bool A = (v > pv) || (v == pv && idx < pi);
            if (want_max != A) { v = pv; idx = pi; }
        }
    }
    u.p2.sv[t] = v; u.p2.si[t] = idx; u.p2.invL[t] = -1;
    __syncthreads();
    if (t < k) u.p2.invL[idx] = t;

    const int f = t & 127;
    const int part = t >> 7;
    const float* hbase = h + (size_t)g * n * H + f;
    float* obase = hout + (size_t)g * k * H + f;
    float mx = -INFINITY, sm = 0.f;
    int j = part;
    for (; j + 12 < k; j += 16) {
        int r0 = u.p2.si[j], r1 = u.p2.si[j + 4], r2 = u.p2.si[j + 8], r3 = u.p2.si[j + 12];
        float s0 = u.p2.sv[j], s1 = u.p2.sv[j + 4], s2 = u.p2.sv[j + 8], s3 = u.p2.sv[j + 12];
        float a0 = hbase[(size_t)r0 * H];
        float a1 = hbase[(size_t)r1 * H];
        float a2 = hbase[(size_t)r2 * H];
        float a3 = hbase[(size_t)r3 * H];
        float v0 = a0 * s0, v1 = a1 * s1, v2 = a2 * s2, v3 = a3 * s3;
        obase[(size_t)j * H] = v0;
        obase[(size_t)(j + 4) * H] = v1;
        obase[(size_t)(j + 8) * H] = v2;
        obase[(size_t)(j + 12) * H] = v3;
        mx = fmaxf(mx, v0); sm += v0;
        mx = fmaxf(mx, v1); sm += v1;
        mx = fmaxf(mx, v2); sm += v2;
        mx = fmaxf(mx, v3); sm += v3;
    }
    for (; j < k; j += 4) {
        float vv = hbase[(size_t)u.p2.si[j] * H] * u.p2.sv[j];
        obase[(size_t)j * H] = vv;
        mx = fmaxf(mx, vv); sm += vv;
    }
    u.p2.smax[part][f] = mx;
    u.p2.ssum[part][f] = sm;
    if (t < n) u.p2.cnt[t] = 0;
    __syncthreads();
    if (t < 128) {
        float m0 = fmaxf(fmaxf(u.p2.smax[0][t], u.p2.smax[1][t]),
                         fmaxf(u.p2.smax[2][t], u.p2.smax[3][t]));
        float s0 = (u.p2.ssum[0][t] + u.p2.ssum[1][t]) + (u.p2.ssum[2][t] + u.p2.ssum[3][t]);
        z[g * 256 + t] = m0;                       // zstore=1 for layer 1
        z[g * 256 + 128 + t] = s0 / (float)k;
    }

    // CSR build + inline remap (src = original edge list)
    const int gk = g * k;
    for (int i = t; i < EPG; i += 512) {
        int s = ei[e0 + i];
        ushort2 p = make_ushort2(DEAD, DEAD);
        {
            int ls = u.p2.invL[s - base];
            int ld = u.p2.invL[ei[NE + e0 + i] - base];
            if (ls < 0 || ld < 0) {
                out_s[e0 + i] = -1;
            } else {
                out_s[e0 + i] = gk + ls;
                out_d[e0 + i] = gk + ld;
                p = make_ushort2((unsigned short)ls, (unsigned short)ld);
                atomicAdd(&u.p2.cnt[ld], 1);
            }
        }
        u.p2.eloc[i] = p;
    }
    __syncthreads();
    const int a = (t < n) ? u.p2.cnt[t] : 0;
    const int lane = t & 63, w = t >> 6;
    int xv = a;
#pragma unroll
    for (int o = 1; o < 64; o <<= 1) {
        int y = __shfl_up(xv, o);
        if (lane >= o) xv += y;
    }
    if (lane == 63) u.p2.wsum[w] = xv;
    __syncthreads();
    int woff = 0;
    for (int ww = 0; ww < w; ww++) woff += u.p2.wsum[ww];
    const int incl = xv + woff;
    const int excl = incl - a;
    if (t < n) { u.p2.basep[t] = excl; u.p2.cnt[t] = 0; rowptr[g * RPS + t] = excl; }
    if (t == 511) rowptr[g * RPS + n] = incl;
    __syncthreads();
    for (int i = t; i < EPG; i += 512) {
        ushort2 pe = u.p2.eloc[i];
        if (pe.x != DEAD) {
            int pos = u.p2.basep[pe.y] + atomicAdd(&u.p2.cnt[pe.y], 1);
            col[e0 + pos] = pe.x;
        }
    }
}

// ------- FUSED topk + gather/gate + readout + CSR-build/remap (layers 2/3) ------
// R16-proven. one block (512 threads) per graph.
__global__ __launch_bounds__(512) void topk_pool_kernel(
    const float* __restrict__ h, const float* __restrict__ score,
    int n, int k, float* __restrict__ hout, float* __restrict__ z, int zstore,
    const int* __restrict__ src_s, const int* __restrict__ src_d,
    int* __restrict__ out_s, int* __restrict__ out_d,
    int* __restrict__ rowptr, unsigned short* __restrict__ col, int do_csr) {
    __shared__ float sv[512];
    __shared__ int si[512];
    __shared__ int invL[512];
    __shared__ float smax[4][128];
    __shared__ float ssum[4][128];
    __shared__ ushort2 eloc[EPG];
    __shared__ int cnt[512];
    __shared__ int basep[512];
    __shared__ int wsum[8];
    const int g = blockIdx.x;
    const int t = threadIdx.x;
    float v = (t < n) ? score[g * n + t] : -INFINITY;
    int idx = t;
    for (int size = 2; size <= 512; size <<= 1) {
        const bool desc = ((t & size) == 0);
        for (int stride = size >> 1; stride > 0; stride >>= 1) {
            float pv; int pi;
            if (stride >= 64) {
                sv[t] = v; si[t] = idx;
                __syncthreads();
                pv = sv[t ^ stride]; pi = si[t ^ stride];
                __syncthreads();
            } else {
                pv = __shfl_xor(v, stride);
                pi = __shfl_xor(idx, stride);
            }
            const bool left = ((t & stride) == 0);
            const bool want_max = (desc == left);
            const bool A = (v > pv) || (v == pv && idx < pi);
            if (want_max != A) { v = pv; idx = pi; }
        }
    }
    sv[t] = v; si[t] = idx; invL[t] = -1;
    __syncthreads();
    if (t < k) invL[idx] = t;

    const int f = t & 127;
    const int part = t >> 7;
    const float* hbase = h + (size_t)g * n * H + f;
    float* obase = hout + (size_t)g * k * H + f;
    float mx = -INFINITY, sm = 0.f;
    int j = part;
    for (; j + 12 < k; j += 16) {
        int r0 = si[j], r1 = si[j + 4], r2 = si[j + 8], r3 = si[j + 12];
        float s0 = sv[j], s1 = sv[j + 4], s2 = sv[j + 8], s3 = sv[j + 12];
        float a0 = hbase[(size_t)r0 * H];
        float a1 = hbase[(size_t)r1 * H];
        float a2 = hbase[(size_t)r2 * H];
        float a3 = hbase[(size_t)r3 * H];
        float v0 = a0 * s0, v1 = a1 * s1, v2 = a2 * s2, v3 = a3 * s3;
        obase[(size_t)j * H] = v0;
        obase[(size_t)(j + 4) * H] = v1;
        obase[(size_t)(j + 8) * H] = v2;
        obase[(size_t)(j + 12) * H] = v3;
        mx = fmaxf(mx, v0); sm += v0;
        mx = fmaxf(mx, v1); sm += v1;
        mx = fmaxf(mx, v2); sm += v2;
        mx = fmaxf(mx, v3); sm += v3;
    }
    for (; j < k; j += 4) {
        float vv = hbase[(size_t)si[j] * H] * sv[j];
        obase[(size_t)j * H] = vv;
        mx = fmaxf(mx, vv); sm += vv;
    }
    smax[part][f] = mx;
    ssum[part][f] = sm;
    if (t < n) cnt[t] = 0;
    __syncthreads();
    if (t < 128) {
        float m0 = fmaxf(fmaxf(smax[0][t], smax[1][t]), fmaxf(smax[2][t], smax[3][t]));
        float s0 = (ssum[0][t] + ssum[1][t]) + (ssum[2][t] + ssum[3][t]);
        if (zstore) {
            z[g * 256 + t] = m0;
            z[g * 256 + 128 + t] = s0 / (float)k;
        } else {
            z[g * 256 + t] += m0;
            z[g * 256 + 128 + t] += s0 / (float)k;
        }
    }
    if (!do_csr) return;

    const int basen = g * n;
    const int gk = g * k;
    const int e0 = g * EPG;
    for (int i = t; i < EPG; i += 512) {
        int s = src_s[e0 + i];
        ushort2 p = make_ushort2(DEAD, DEAD);
        if (s >= 0) {
            int ls = invL[s - basen];
            int ld = invL[src_d[e0 + i] - basen];
            if (ls < 0 || ld < 0) {
                out_s[e0 + i] = -1;
            } else {
                out_s[e0 + i] = gk + ls;
                out_d[e0 + i] = gk + ld;
                p = make_ushort2((unsigned short)ls, (unsigned short)ld);
                atomicAdd(&cnt[ld], 1);
            }
        } else {
            out_s[e0 + i] = -1;
        }
        eloc[i] = p;
    }
    __syncthreads();
    const int a = (t < n) ? cnt[t] : 0;
    const int lane = t & 63, w = t >> 6;
    int xv = a;
#pragma unroll
    for (int o = 1; o < 64; o <<= 1) {
        int y = __shfl_up(xv, o);
        if (lane >= o) xv += y;
    }
    if (lane == 63) wsum[w] = xv;
    __syncthreads();
    int woff = 0;
    for (int ww = 0; ww < w; ww++) woff += wsum[ww];
    const int incl = xv + woff;
    const int excl = incl - a;
    if (t < n) { basep[t] = excl; cnt[t] = 0; rowptr[g * RPS + t] = excl; }
    if (t == 511) rowptr[g * RPS + n] = incl;
    __syncthreads();
    for (int i = t; i < EPG; i += 512) {
        ushort2 pe = eloc[i];
        if (pe.x != DEAD) {
            int pos = basep[pe.y] + atomicAdd(&cnt[pe.y], 1);
            col[e0 + pos] = pe.x;
        }
    }
}

// ---------------- layers 2/3 aggregation: CSR gather, no atomics ----------
__global__ __launch_bounds__(512) void agg_gather_kernel(
    const float* __restrict__ h, const int* __restrict__ rowptr,
    const unsigned short* __restrict__ col, int* __restrict__ agg, int n) {
    __shared__ int hsq[K1 * 16];
    __shared__ unsigned short colL[EPG];
    __shared__ int rp[N0 + 1];
    const int g = blockIdx.x;
    const int fq = blockIdx.y * 16;
    const int t = threadIdx.x;
    const int base = g * n;
    const int e0 = g * EPG;
    const int nf4 = n * 4;
    for (int i = t; i < nf4; i += 512) {
        int m = i >> 2, j = (i & 3) * 4;
        float4 v = *(const float4*)(h + (size_t)(base + m) * H + fq + j);
        int4 q;
        q.x = __float2int_rn(v.x * SCALE2);
        q.y = __float2int_rn(v.y * SCALE2);
        q.z = __float2int_rn(v.z * SCALE2);
        q.w = __float2int_rn(v.w * SCALE2);
        *(int4*)(hsq + m * 16 + j) = q;
    }
    {
        const unsigned int* src = (const unsigned int*)(col + e0);
        unsigned int* dst = (unsigned int*)colL;
        for (int i = t; i < EPG / 2; i += 512) dst[i] = src[i];
    }
    for (int i = t; i <= n; i += 512) rp[i] = rowptr[g * RPS + i];
    __syncthreads();
    const int sub = t >> 4;
    const int f = t & 15;
    for (int m = sub; m < n; m += 32) {
        int r0 = rp[m], r1 = rp[m + 1];
        int acc = 0;
        int r = r0;
        for (; r + 3 < r1; r += 4) {
            int c0 = colL[r], c1 = colL[r + 1], c2 = colL[r + 2], c3 = colL[r + 3];
            int a0 = hsq[c0 * 16 + f];
            int a1 = hsq[c1 * 16 + f];
            int a2 = hsq[c2 * 16 + f];
            int a3 = hsq[c3 * 16 + f];
            acc += (a0 + a1) + (a2 + a3);
        }
        for (; r < r1; r++) acc += hsq[colL[r] * 16 + f];
        agg[(size_t)(base + m) * H + fq + f] = acc;
    }
}

// out[i][o] = relu( sum_k agg[i][k]*Wrel[o][k] + sum_k hin[i][k]*Wroot[o][k] + b[o] )
// R12/R14/R16-proven config: 64x128 tile, 256 threads, 4x8 micro-tile,
// o4-split B cols, Bs padded 132, fused score epilogue.
__global__ __launch_bounds__(256) void conv_gemm_kernel(
    const int* __restrict__ agg, const float* __restrict__ hin,
    const float* __restrict__ Wrel, const float* __restrict__ Wroot,
    const float* __restrict__ bias, const float* __restrict__ pw,
    float* __restrict__ out, float* __restrict__ score, int M) {
    __shared__ float As[32][68];
    __shared__ float Bs[32][132];
    const int t = threadIdx.x;
    const int row0 = blockIdx.x * 64;
    const int tx = t & 15;
    const int ty = t >> 4;
    const int o4 = tx * 4;
    const int r4 = ty * 4;

    float acc[4][8];
#pragma unroll
    for (int i = 0; i < 4; i++)
#pragma unroll
        for (int j = 0; j < 8; j++) acc[i][j] = 0.f;

#pragma unroll 1
    for (int kc = 0; kc < 256; kc += 32) {
        const float* Wsrc = (kc < 128) ? (Wrel + kc) : (Wroot + (kc - 128));
#pragma unroll
        for (int i = 0; i < 2; i++) {
            int li = t + i * 256;
            int r = li >> 3, q = li & 7;
            int grow = row0 + r;
            float4 v = make_float4(0.f, 0.f, 0.f, 0.f);
            if (grow < M) {
                if (kc < 128) {
                    int4 iv = *(const int4*)(agg + (size_t)grow * H + kc + q * 4);
                    v.x = (float)iv.x * INV2;
                    v.y = (float)iv.y * INV2;
                    v.z = (float)iv.z * INV2;
                    v.w = (float)iv.w * INV2;
                } else {
                    v = *(const float4*)(hin + (size_t)grow * H + (kc - 128) + q * 4);
                }
            }
            As[q * 4 + 0][r] = v.x;
            As[q * 4 + 1][r] = v.y;
            As[q * 4 + 2][r] = v.z;
            As[q * 4 + 3][r] = v.w;
        }
#pragma unroll
        for (int i = 0; i < 4; i++) {
            int li = t + i * 256;
            int o = li >> 3, q = li & 7;
            float4 v = *(const float4*)(Wsrc + (size_t)o * H + q * 4);
            Bs[q * 4 + 0][o] = v.x;
            Bs[q * 4 + 1][o] = v.y;
            Bs[q * 4 + 2][o] = v.z;
            Bs[q * 4 + 3][o] = v.w;
        }
        __syncthreads();
#pragma unroll
        for (int kk = 0; kk < 32; kk++) {
            const float4 a0 = *(const float4*)&As[kk][r4];
            const float4 b0 = *(const float4*)&Bs[kk][o4];
            const float4 b1 = *(const float4*)&Bs[kk][64 + o4];
            float av[4] = {a0.x, a0.y, a0.z, a0.w};
            float bv[8] = {b0.x, b0.y, b0.z, b0.w, b1.x, b1.y, b1.z, b1.w};
#pragma unroll
            for (int ii = 0; ii < 4; ii++)
#pragma unroll
                for (int jj = 0; jj < 8; jj++)
                    acc[ii][jj] = fmaf(av[ii], bv[jj], acc[ii][jj]);
        }
        __syncthreads();
    }

    float wv[8];
#pragma unroll
    for (int j = 0; j < 4; j++) { wv[j] = pw[o4 + j]; wv[4 + j] = pw[64 + o4 + j]; }
    float n2 = 0.f;
#pragma unroll
    for (int j = 0; j < 8; j++) n2 = fmaf(wv[j], wv[j], n2);
#pragma unroll
    for (int s = 1; s < 16; s <<= 1) n2 += __shfl_xor(n2, s);
    const float rnorm = 1.0f / sqrtf(n2);

#pragma unroll
    for (int ii = 0; ii < 4; ii++) {
        int grow = row0 + r4 + ii;
        float4 o0, o1;
        o0.x = fmaxf(acc[ii][0] + bias[o4 + 0], 0.f);
        o0.y = fmaxf(acc[ii][1] + bias[o4 + 1], 0.f);
        o0.z = fmaxf(acc[ii][2] + bias[o4 + 2], 0.f);
        o0.w = fmaxf(acc[ii][3] + bias[o4 + 3], 0.f);
        o1.x = fmaxf(acc[ii][4] + bias[64 + o4 + 0], 0.f);
        o1.y = fmaxf(acc[ii][5] + bias[64 + o4 + 1], 0.f);
        o1.z = fmaxf(acc[ii][6] + bias[64 + o4 + 2], 0.f);
        o1.w = fmaxf(acc[ii][7] + bias[64 + o4 + 3], 0.f);
        float d = 0.f;
        d = fmaf(o0.x, wv[0], d); d = fmaf(o0.y, wv[1], d);
        d = fmaf(o0.z, wv[2], d); d = fmaf(o0.w, wv[3], d);
        d = fmaf(o1.x, wv[4], d); d = fmaf(o1.y, wv[5], d);
        d = fmaf(o1.z, wv[6], d); d = fmaf(o1.w, wv[7], d);
#pragma unroll
        for (int s = 1; s < 16; s <<= 1) d += __shfl_xor(d, s);
        if (grow < M) {
            *(float4*)(out + (size_t)grow * H + o4) = o0;
            *(float4*)(out + (size_t)grow * H + 64 + o4) = o1;
            if (tx == 0) score[grow] = tanhf(d * rnorm);
        }
    }
}

// ---------------- head: FUSED fc + batchnorm + relu ----------------
__global__ __launch_bounds__(256) void fc_bn_kernel(
    const float* __restrict__ in, const float* __restrict__ W,
    const float* __restrict__ bias, const float* __restrict__ gam,
    const float* __restrict__ bet, float* __restrict__ out, int Kdim, int Odim) {
    __shared__ float wL[256];
    __shared__ float red[256];
    const int o = blockIdx.x;
    const int t = threadIdx.x;
    for (int i = t; i < Kdim; i += 256) wL[i] = W[(size_t)o * Kdim + i];
    __syncthreads();
    float v = 0.f;
    if (t < G) {
        v = bias[o];
        const float* row = in + (size_t)t * Kdim;
        for (int kk = 0; kk < Kdim; kk++) v += row[kk] * wL[kk];
    }
    red[t] = (t < G) ? v : 0.f;
    __syncthreads();
    for (int s = 128; s > 0; s >>= 1) {
        if (t < s) red[t] += red[t + s];
        __syncthreads();
    }
    float m = red[0] / (float)G;
    __syncthreads();
    red[t] = (t < G) ? v * v : 0.f;
    __syncthreads();
    for (int s = 128; s > 0; s >>= 1) {
        if (t < s) red[t] += red[t + s];
        __syncthreads();
    }
    float var = red[0] / (float)G - m * m;
    float invs = 1.0f / sqrtf(var + 1e-5f);
    if (t < G) out[(size_t)t * Odim + o] = fmaxf((v - m) * invs * gam[o] + bet[o], 0.f);
}

__global__ void head_kernel(const float* __restrict__ fc2, const float* __restrict__ W,
                            const float* __restrict__ b, float* __restrict__ out) {
    int g = blockIdx.x * blockDim.x + threadIdx.x;
    if (g >= G) return;
    float l0 = b[0], l1 = b[1];
    for (int k = 0; k < 64; k++) {
        float v = fc2[g * 64 + k];
        l0 += v * W[k];
        l1 += v * W[64 + k];
    }
    float mx = fmaxf(l0, l1);
    float e0 = expf(l0 - mx), e1 = expf(l1 - mx);
    float s = e0 + e1;
    out[g * 2 + 0] = e0 / s;
    out[g * 2 + 1] = e1 / s;
}

extern "C" void kernel_launch(void* const* d_in, const int* in_sizes, int n_in,
                              void* d_out, int out_size, void* d_ws, size_t ws_size,
                              hipStream_t stream) {
    (void)in_sizes; (void)n_in; (void)out_size; (void)ws_size;

    const float* x      = (const float*)d_in[0];
    const int*   ei     = (const int*)d_in[1];
    const float* Wrel1  = (const float*)d_in[2];
    const float* Wroot1 = (const float*)d_in[3];
    const float* b1     = (const float*)d_in[4];
    const float* Wrel2  = (const float*)d_in[5];
    const float* Wroot2 = (const float*)d_in[6];
    const float* b2     = (const float*)d_in[7];
    const float* Wrel3  = (const float*)d_in[8];
    const float* Wroot3 = (const float*)d_in[9];
    const float* b3     = (const float*)d_in[10];
    const float* pw1    = (const float*)d_in[11];
    const float* pw2    = (const float*)d_in[12];
    const float* pw3    = (const float*)d_in[13];
    const float* lin1w  = (const float*)d_in[14];
    const float* lin1b  = (const float*)d_in[15];
    const float* lin2w  = (const float*)d_in[16];
    const float* lin2b  = (const float*)d_in[17];
    const float* lin3w  = (const float*)d_in[18];
    const float* lin3b  = (const float*)d_in[19];
    const float* bn1g   = (const float*)d_in[20];
    const float* bn1b   = (const float*)d_in[21];
    const float* bn2g   = (const float*)d_in[22];
    const float* bn2b   = (const float*)d_in[23];

    float* bufA  = (float*)d_ws;                  // NT0*H floats
    float* bufB  = bufA + (size_t)NT0 * H;        // NT1*H floats
    float* score = bufB + (size_t)NT1 * H;        // NT0
    int*   cs    = (int*)(score + NT0);           // NE
    int*   cd    = cs + NE;                       // NE
    float* z     = (float*)(cd + NE);             // G*256
    float* f1    = z + G * 256;                   // G*128
    float* f2    = f1 + G * H;                    // G*64
    int*   rowp  = (int*)(f2 + G * 64);           // G*RPS ints
    unsigned short* col = (unsigned short*)(rowp + G * RPS);   // NE ushorts

    // ---- layer 1 (mega-fused) ----
    layer1_kernel<<<G, 512, 0, stream>>>(x, ei, Wrel1, Wroot1, b1, pw1,
                                         bufA, bufB, z, cs, cd, rowp, col);

    // ---- layer 2 ----
    agg_gather_kernel<<<dim3(G, 8), 512, 0, stream>>>(bufB, rowp, col, (int*)bufA, K1);
    conv_gemm_kernel<<<cdiv(NT1, 64), 256, 0, stream>>>((const int*)bufA, bufB, Wrel2, Wroot2, b2, pw2, bufA, score, NT1);
    topk_pool_kernel<<<G, 512, 0, stream>>>(bufA, score, K1, K2, bufB, z, 0,
                                            cs, cd, cs, cd, rowp, col, 1);

    // ---- layer 3 ----
    agg_gather_kernel<<<dim3(G, 8), 512, 0, stream>>>(bufB, rowp, col, (int*)bufA, K2);
    conv_gemm_kernel<<<cdiv(NT2, 64), 256, 0, stream>>>((const int*)bufA, bufB, Wrel3, Wroot3, b3, pw3, bufA, score, NT2);
    topk_pool_kernel<<<G, 512, 0, stream>>>(bufA, score, K2, K3, bufB, z, 0,
                                            cs, cd, cs, cd, rowp, col, 0);

    // ---- head ----
    fc_bn_kernel<<<128, 256, 0, stream>>>(z, lin1w, lin1b, bn1g, bn1b, f1, 256, 128);
    fc_bn_kernel<<<64, 256, 0, stream>>>(f1, lin2w, lin2b, bn2g, bn2b, f2, 128, 64);
    head_kernel<<<1, 256, 0, stream>>>(f2, lin3w, lin3b, (float*)d_out);
}